// Round 3
// baseline (1244.537 us; speedup 1.0000x reference)
//
#include <hip/hip_runtime.h>
#include <hip/hip_bf16.h>
#include <math.h>

#define N_NODES 100000
#define F_IN 512
#define H_DIM 16
#define C_DIM 40

#define BUCKET_SHIFT 7                 // 128 nodes per bucket
#define BUCKET_NODES 128
#define NBUCK 782                      // ceil(100000 / 128)
#define CHUNK 16384                    // edges per partition block
#define SRC_MASK 0x1FFFF               // 17 bits (N < 131072)

// ---------------- degree histogram / dinv ----------------

__global__ void hist_kernel(const int* __restrict__ dst, int* __restrict__ cnt, int E) {
    int e = blockIdx.x * blockDim.x + threadIdx.x;
    if (e < E) atomicAdd(&cnt[dst[e]], 1);
}

__global__ void dinv_kernel(const int* __restrict__ cnt, float* __restrict__ dinv, int N) {
    int i = blockIdx.x * blockDim.x + threadIdx.x;
    if (i < N) dinv[i] = rsqrtf((float)(cnt[i] + 1));  // +1 = self-loop
}

// ---------------- per-bucket edge counts: BC[b] = sum of deg over bucket's nodes ----------------

__global__ void __launch_bounds__(128) bucket_sum_kernel(const int* __restrict__ S,
                                                         int* __restrict__ BC, int N) {
    int n = blockIdx.x * BUCKET_NODES + threadIdx.x;
    int v = (n < N) ? S[n] : 0;
#pragma unroll
    for (int off = 32; off > 0; off >>= 1) v += __shfl_down(v, off, 64);
    __shared__ int tmp[2];
    if ((threadIdx.x & 63) == 0) tmp[threadIdx.x >> 6] = v;
    __syncthreads();
    if (threadIdx.x == 0) BC[blockIdx.x] = tmp[0] + tmp[1];
}

// ---------------- exclusive scan of BC[NBUCK] -> BO[NBUCK+1], init cursor ----------------

__global__ void __launch_bounds__(1024) scan_small_kernel(const int* __restrict__ BC,
                                                          int* __restrict__ BO,
                                                          int* __restrict__ cursor) {
    __shared__ int buf[2][1024];
    int tid = threadIdx.x;
    int v = (tid < NBUCK) ? BC[tid] : 0;
    int cur = 0;
    buf[0][tid] = v;
    __syncthreads();
    for (int off = 1; off < 1024; off <<= 1) {
        int t = buf[cur][tid] + ((tid >= off) ? buf[cur][tid - off] : 0);
        cur ^= 1;
        buf[cur][tid] = t;
        __syncthreads();
    }
    int inc = buf[cur][tid];
    if (tid < NBUCK) {
        int ex = inc - v;
        BO[tid] = ex;
        cursor[tid] = ex;
    }
    if (tid == NBUCK - 1) BO[NBUCK] = inc;  // == E
}

// ---------------- radix partition by dst bucket; packed = (local_dst<<17)|src ----------------

__global__ void __launch_bounds__(256) partition_kernel(const int* __restrict__ src,
                                                        const int* __restrict__ dst,
                                                        int* __restrict__ cursor,
                                                        int* __restrict__ packed, int E) {
    __shared__ int cnt[NBUCK];
    __shared__ int base[NBUCK];
    int start = blockIdx.x * CHUNK;
    int end = start + CHUNK < E ? start + CHUNK : E;
    for (int i = threadIdx.x; i < NBUCK; i += 256) cnt[i] = 0;
    __syncthreads();
    for (int i = start + threadIdx.x; i < end; i += 256)
        atomicAdd(&cnt[dst[i] >> BUCKET_SHIFT], 1);
    __syncthreads();
    for (int i = threadIdx.x; i < NBUCK; i += 256) {
        int c = cnt[i];
        base[i] = c ? atomicAdd(&cursor[i], c) : 0;
        cnt[i] = 0;  // reuse as local position
    }
    __syncthreads();
    for (int i = start + threadIdx.x; i < end; i += 256) {
        int d = dst[i];
        int b = d >> BUCKET_SHIFT;
        int p = base[b] + atomicAdd(&cnt[b], 1);
        packed[p] = ((d & (BUCKET_NODES - 1)) << 17) | src[i];
    }
}

// ---------------- GEMM1: g1 = (x @ W1) * dinv, 1 row per thread ----------------

__global__ void __launch_bounds__(256) gemm1_kernel(const float* __restrict__ x,
                                                    const float* __restrict__ W1,
                                                    const float* __restrict__ dinv,
                                                    float* __restrict__ g1, int N) {
    __shared__ float w[F_IN * H_DIM];  // 32 KB
    {
        float4* w4s = (float4*)w;
        const float4* W4 = (const float4*)W1;
        for (int i = threadIdx.x; i < F_IN * H_DIM / 4; i += 256) w4s[i] = W4[i];
    }
    __syncthreads();
    int row = blockIdx.x * 256 + threadIdx.x;
    if (row >= N) return;
    const float4* xr = (const float4*)(x + (size_t)row * F_IN);
    float acc[H_DIM];
#pragma unroll
    for (int k = 0; k < H_DIM; k++) acc[k] = 0.0f;
    const float4* w4 = (const float4*)w;
    for (int f4 = 0; f4 < F_IN / 4; ++f4) {
        float4 xv = xr[f4];
        float xs[4] = {xv.x, xv.y, xv.z, xv.w};
#pragma unroll
        for (int q = 0; q < 4; q++) {
            float wq[H_DIM];
#pragma unroll
            for (int p = 0; p < 4; p++) *(float4*)&wq[4 * p] = w4[(f4 * 4 + q) * 4 + p];
            float s = xs[q];
#pragma unroll
            for (int k = 0; k < H_DIM; k++) acc[k] += s * wq[k];
        }
    }
    float di = dinv[row];
    float4* o = (float4*)(g1 + (size_t)row * H_DIM);
#pragma unroll
    for (int p = 0; p < 4; p++)
        o[p] = make_float4(acc[4 * p] * di, acc[4 * p + 1] * di,
                           acc[4 * p + 2] * di, acc[4 * p + 3] * di);
}

// ---------------- bucketed aggregation: LDS accumulator, gather g[src] ----------------

// layer 1: g2 = dinv * relu(dinv*(sum + self) + b1)
__global__ void __launch_bounds__(256) agg1_kernel(const int* __restrict__ BO,
                                                   const int* __restrict__ packed,
                                                   const float* __restrict__ g1,
                                                   const float* __restrict__ dinv,
                                                   const float* __restrict__ b1,
                                                   float* __restrict__ g2, int N) {
    __shared__ float acc[BUCKET_NODES * H_DIM];  // 8 KB
    int b = blockIdx.x;
    for (int i = threadIdx.x; i < BUCKET_NODES * H_DIM; i += 256) acc[i] = 0.0f;
    __syncthreads();
    int lo = BO[b], hi = BO[b + 1];
    int k = threadIdx.x & 15;
    int eg = threadIdx.x >> 4;  // 16 edge-groups
    int e = lo + eg;
    for (; e + 48 < hi; e += 64) {
        int p0 = packed[e], p1 = packed[e + 16], p2 = packed[e + 32], p3 = packed[e + 48];
        float v0 = g1[(p0 & SRC_MASK) * H_DIM + k];
        float v1 = g1[(p1 & SRC_MASK) * H_DIM + k];
        float v2 = g1[(p2 & SRC_MASK) * H_DIM + k];
        float v3 = g1[(p3 & SRC_MASK) * H_DIM + k];
        atomicAdd(&acc[(p0 >> 17) * H_DIM + k], v0);
        atomicAdd(&acc[(p1 >> 17) * H_DIM + k], v1);
        atomicAdd(&acc[(p2 >> 17) * H_DIM + k], v2);
        atomicAdd(&acc[(p3 >> 17) * H_DIM + k], v3);
    }
    for (; e < hi; e += 16) {
        int p0 = packed[e];
        atomicAdd(&acc[(p0 >> 17) * H_DIM + k], g1[(p0 & SRC_MASK) * H_DIM + k]);
    }
    __syncthreads();
    int nbase = b << BUCKET_SHIFT;
    for (int t = threadIdx.x; t < BUCKET_NODES * H_DIM; t += 256) {
        int local = t >> 4, kk = t & 15;
        int n = nbase + local;
        if (n < N) {
            float di = dinv[n];
            float sum = acc[t] + g1[n * H_DIM + kk];  // self-loop (g1 = dinv*h1)
            g2[n * H_DIM + kk] = di * fmaxf(di * sum + b1[kk], 0.0f);
        }
    }
}

// layer 2: s2 = sum + self (dinv, W2, b2 applied in final)
__global__ void __launch_bounds__(256) agg2_kernel(const int* __restrict__ BO,
                                                   const int* __restrict__ packed,
                                                   const float* __restrict__ g2,
                                                   float* __restrict__ s2, int N) {
    __shared__ float acc[BUCKET_NODES * H_DIM];
    int b = blockIdx.x;
    for (int i = threadIdx.x; i < BUCKET_NODES * H_DIM; i += 256) acc[i] = 0.0f;
    __syncthreads();
    int lo = BO[b], hi = BO[b + 1];
    int k = threadIdx.x & 15;
    int eg = threadIdx.x >> 4;
    int e = lo + eg;
    for (; e + 48 < hi; e += 64) {
        int p0 = packed[e], p1 = packed[e + 16], p2 = packed[e + 32], p3 = packed[e + 48];
        float v0 = g2[(p0 & SRC_MASK) * H_DIM + k];
        float v1 = g2[(p1 & SRC_MASK) * H_DIM + k];
        float v2 = g2[(p2 & SRC_MASK) * H_DIM + k];
        float v3 = g2[(p3 & SRC_MASK) * H_DIM + k];
        atomicAdd(&acc[(p0 >> 17) * H_DIM + k], v0);
        atomicAdd(&acc[(p1 >> 17) * H_DIM + k], v1);
        atomicAdd(&acc[(p2 >> 17) * H_DIM + k], v2);
        atomicAdd(&acc[(p3 >> 17) * H_DIM + k], v3);
    }
    for (; e < hi; e += 16) {
        int p0 = packed[e];
        atomicAdd(&acc[(p0 >> 17) * H_DIM + k], g2[(p0 & SRC_MASK) * H_DIM + k]);
    }
    __syncthreads();
    int nbase = b << BUCKET_SHIFT;
    for (int t = threadIdx.x; t < BUCKET_NODES * H_DIM; t += 256) {
        int local = t >> 4, kk = t & 15;
        int n = nbase + local;
        if (n < N) s2[n * H_DIM + kk] = acc[t] + g2[n * H_DIM + kk];
    }
}

// ---------------- final: v = dinv*s2; logits = v@W2 + b2; log_softmax; coalesced writes ----------------

__global__ void __launch_bounds__(256) final_kernel(const float* __restrict__ s2,
                                                    const float* __restrict__ dinv,
                                                    const float* __restrict__ W2,
                                                    const float* __restrict__ b2,
                                                    float* __restrict__ out, int N) {
    __shared__ float w2s[H_DIM * C_DIM];
    __shared__ float b2s[C_DIM];
    __shared__ float stage[256 * 41];
    for (int i = threadIdx.x; i < H_DIM * C_DIM; i += 256) w2s[i] = W2[i];
    if (threadIdx.x < C_DIM) b2s[threadIdx.x] = b2[threadIdx.x];
    __syncthreads();
    int n = blockIdx.x * 256 + threadIdx.x;
    int cn = n < N ? n : 0;
    float di = dinv[cn];
    float v[H_DIM];
    const float4* sv = (const float4*)(s2 + (size_t)cn * H_DIM);
#pragma unroll
    for (int p = 0; p < 4; p++) {
        float4 t = sv[p];
        v[4 * p] = di * t.x; v[4 * p + 1] = di * t.y;
        v[4 * p + 2] = di * t.z; v[4 * p + 3] = di * t.w;
    }
    float lg[C_DIM];
    float m = -1e30f;
    for (int c = 0; c < C_DIM; c++) {
        float a = b2s[c];
#pragma unroll
        for (int k = 0; k < H_DIM; k++) a += v[k] * w2s[k * C_DIM + c];
        lg[c] = a;
        m = fmaxf(m, a);
    }
    float ssum = 0.0f;
    for (int c = 0; c < C_DIM; c++) ssum += __expf(lg[c] - m);
    float lse = m + __logf(ssum);

    size_t base = (size_t)blockIdx.x * 256 * C_DIM;
    size_t lim = (size_t)N * C_DIM;
    for (int c = 0; c < C_DIM; c++) stage[threadIdx.x * 41 + c] = lg[c] - lse;
    __syncthreads();
    for (int i = threadIdx.x; i < 256 * C_DIM; i += 256) {
        int nn = i / C_DIM, c = i - nn * C_DIM;
        size_t g = base + i;
        if (g < lim) out[g] = stage[nn * 41 + c];
    }
    __syncthreads();
    for (int c = 0; c < C_DIM; c++) stage[threadIdx.x * 41 + c] = lg[c];
    __syncthreads();
    for (int i = threadIdx.x; i < 256 * C_DIM; i += 256) {
        int nn = i / C_DIM, c = i - nn * C_DIM;
        size_t g = base + i;
        if (g < lim) out[lim + g] = stage[nn * 41 + c];
    }
}

// ---------------- launch ----------------

extern "C" void kernel_launch(void* const* d_in, const int* in_sizes, int n_in,
                              void* d_out, int out_size, void* d_ws, size_t ws_size,
                              hipStream_t stream) {
    const float* x  = (const float*)d_in[0];
    const int* ei   = (const int*)d_in[1];
    const float* W1 = (const float*)d_in[2];
    const float* b1 = (const float*)d_in[3];
    const float* W2 = (const float*)d_in[4];
    const float* b2 = (const float*)d_in[5];
    float* out = (float*)d_out;

    const int N = N_NODES;
    const int E = in_sizes[1] / 2;
    const int* src = ei;
    const int* dst = ei + E;

    // ws layout (4-byte units, 16 B-aligned chunks):
    // S[N] | BC[784] | BO[784] | cursor[784] | dinv[N] | g1[16N] | g2[16N] | packed[E]
    int* S      = (int*)d_ws;
    int* BC     = S + N;
    int* BO     = BC + 784;
    int* cursor = BO + 784;
    float* dinv = (float*)(cursor + 784);
    float* g1   = dinv + N;
    float* g2   = g1 + 16 * N;
    int* packed = (int*)(g2 + 16 * N);
    float* s2   = g1;  // g1 dead after agg1

    hipMemsetAsync(S, 0, (size_t)N * sizeof(int), stream);
    hist_kernel<<<(E + 255) / 256, 256, 0, stream>>>(dst, S, E);
    dinv_kernel<<<(N + 255) / 256, 256, 0, stream>>>(S, dinv, N);
    bucket_sum_kernel<<<NBUCK, 128, 0, stream>>>(S, BC, N);
    scan_small_kernel<<<1, 1024, 0, stream>>>(BC, BO, cursor);
    partition_kernel<<<(E + CHUNK - 1) / CHUNK, 256, 0, stream>>>(src, dst, cursor, packed, E);

    gemm1_kernel<<<(N + 255) / 256, 256, 0, stream>>>(x, W1, dinv, g1, N);
    agg1_kernel<<<NBUCK, 256, 0, stream>>>(BO, packed, g1, dinv, b1, g2, N);
    agg2_kernel<<<NBUCK, 256, 0, stream>>>(BO, packed, g2, s2, N);
    final_kernel<<<(N + 255) / 256, 256, 0, stream>>>(s2, dinv, W2, b2, out, N);
}

// Round 4
// 1153.289 us; speedup vs baseline: 1.0791x; 1.0791x over previous
//
#include <hip/hip_runtime.h>
#include <hip/hip_bf16.h>
#include <math.h>

#define N_NODES 100000
#define F_IN 512
#define H_DIM 16
#define C_DIM 40

#define BUCKET_SHIFT 6                 // 64 nodes per bucket
#define BUCKET_NODES 64
#define NBUCK 1563                     // ceil(100000 / 64)
#define CHUNK 8192                     // edges per partition block
#define SRC_MASK 0x1FFFF               // 17 bits (N < 131072)

// ---------------- degree histogram / dinv ----------------

__global__ void hist_kernel(const int* __restrict__ dst, int* __restrict__ cnt, int E) {
    int e = blockIdx.x * blockDim.x + threadIdx.x;
    if (e < E) atomicAdd(&cnt[dst[e]], 1);
}

__global__ void dinv_kernel(const int* __restrict__ cnt, float* __restrict__ dinv, int N) {
    int i = blockIdx.x * blockDim.x + threadIdx.x;
    if (i < N) dinv[i] = rsqrtf((float)(cnt[i] + 1));  // +1 = self-loop
}

// ---------------- per-bucket edge counts: one wave per bucket ----------------

__global__ void __launch_bounds__(256) bucket_sum_kernel(const int* __restrict__ S,
                                                         int* __restrict__ BC, int N) {
    int bucket = blockIdx.x * 4 + (threadIdx.x >> 6);
    if (bucket >= NBUCK) return;
    int n = bucket * BUCKET_NODES + (threadIdx.x & 63);
    int v = (n < N) ? S[n] : 0;
#pragma unroll
    for (int off = 32; off > 0; off >>= 1) v += __shfl_down(v, off, 64);
    if ((threadIdx.x & 63) == 0) BC[bucket] = v;
}

// ---------------- exclusive scan of BC[NBUCK] -> BO[NBUCK+1], init cursor (2 elems/thread) ----------------

__global__ void __launch_bounds__(1024) scan_small_kernel(const int* __restrict__ BC,
                                                          int* __restrict__ BO,
                                                          int* __restrict__ cursor) {
    __shared__ int buf[2][1024];
    int tid = threadIdx.x;
    int i0 = 2 * tid, i1 = 2 * tid + 1;
    int v0 = (i0 < NBUCK) ? BC[i0] : 0;
    int v1 = (i1 < NBUCK) ? BC[i1] : 0;
    int pair = v0 + v1;
    int cur = 0;
    buf[0][tid] = pair;
    __syncthreads();
    for (int off = 1; off < 1024; off <<= 1) {
        int t = buf[cur][tid] + ((tid >= off) ? buf[cur][tid - off] : 0);
        cur ^= 1;
        buf[cur][tid] = t;
        __syncthreads();
    }
    int inc = buf[cur][tid];
    int ex = inc - pair;
    if (i0 < NBUCK) { BO[i0] = ex;      cursor[i0] = ex; }
    if (i1 < NBUCK) { BO[i1] = ex + v0; cursor[i1] = ex + v0; }
    if (tid == 1023) BO[NBUCK] = inc;  // == E
}

// ---------------- radix partition by dst bucket; packed = (local_dst<<17)|src ----------------

__global__ void __launch_bounds__(256) partition_kernel(const int* __restrict__ src,
                                                        const int* __restrict__ dst,
                                                        int* __restrict__ cursor,
                                                        int* __restrict__ packed, int E) {
    __shared__ int cnt[NBUCK];
    __shared__ int base[NBUCK];
    int start = blockIdx.x * CHUNK;
    int end = start + CHUNK < E ? start + CHUNK : E;
    for (int i = threadIdx.x; i < NBUCK; i += 256) cnt[i] = 0;
    __syncthreads();
    for (int i = start + threadIdx.x; i < end; i += 256)
        atomicAdd(&cnt[dst[i] >> BUCKET_SHIFT], 1);
    __syncthreads();
    for (int i = threadIdx.x; i < NBUCK; i += 256) {
        int c = cnt[i];
        base[i] = c ? atomicAdd(&cursor[i], c) : 0;
        cnt[i] = 0;  // reuse as local position
    }
    __syncthreads();
    for (int i = start + threadIdx.x; i < end; i += 256) {
        int d = dst[i];
        int b = d >> BUCKET_SHIFT;
        int p = base[b] + atomicAdd(&cnt[b], 1);
        packed[p] = ((d & (BUCKET_NODES - 1)) << 17) | src[i];
    }
}

// ---------------- GEMM1: g1 = (x @ W1) * dinv, 1 row per thread ----------------

__global__ void __launch_bounds__(256) gemm1_kernel(const float* __restrict__ x,
                                                    const float* __restrict__ W1,
                                                    const float* __restrict__ dinv,
                                                    float* __restrict__ g1, int N) {
    __shared__ float w[F_IN * H_DIM];  // 32 KB
    {
        float4* w4s = (float4*)w;
        const float4* W4 = (const float4*)W1;
        for (int i = threadIdx.x; i < F_IN * H_DIM / 4; i += 256) w4s[i] = W4[i];
    }
    __syncthreads();
    int row = blockIdx.x * 256 + threadIdx.x;
    if (row >= N) return;
    const float4* xr = (const float4*)(x + (size_t)row * F_IN);
    float acc[H_DIM];
#pragma unroll
    for (int k = 0; k < H_DIM; k++) acc[k] = 0.0f;
    const float4* w4 = (const float4*)w;
    for (int f4 = 0; f4 < F_IN / 4; ++f4) {
        float4 xv = xr[f4];
        float xs[4] = {xv.x, xv.y, xv.z, xv.w};
#pragma unroll
        for (int q = 0; q < 4; q++) {
            float wq[H_DIM];
#pragma unroll
            for (int p = 0; p < 4; p++) *(float4*)&wq[4 * p] = w4[(f4 * 4 + q) * 4 + p];
            float s = xs[q];
#pragma unroll
            for (int k = 0; k < H_DIM; k++) acc[k] += s * wq[k];
        }
    }
    float di = dinv[row];
    float4* o = (float4*)(g1 + (size_t)row * H_DIM);
#pragma unroll
    for (int p = 0; p < 4; p++)
        o[p] = make_float4(acc[4 * p] * di, acc[4 * p + 1] * di,
                           acc[4 * p + 2] * di, acc[4 * p + 3] * di);
}

// ---------------- bucketed aggregation, unroll-8 gather, in-kernel epilogue ----------------

// layer 1: g2 = dinv * relu(dinv*(sum + self) + b1)
__global__ void __launch_bounds__(256) agg1_kernel(const int* __restrict__ BO,
                                                   const int* __restrict__ packed,
                                                   const float* __restrict__ g1,
                                                   const float* __restrict__ dinv,
                                                   const float* __restrict__ b1,
                                                   float* __restrict__ g2, int N) {
    __shared__ float acc[BUCKET_NODES * H_DIM];  // 4 KB
    int b = blockIdx.x;
    for (int i = threadIdx.x; i < BUCKET_NODES * H_DIM; i += 256) acc[i] = 0.0f;
    __syncthreads();
    int lo = BO[b], hi = BO[b + 1];
    int k = threadIdx.x & 15;
    int eg = threadIdx.x >> 4;  // 16 edge-groups
    int e = lo + eg;
    for (; e + 112 < hi; e += 128) {
        int p[8];
        float v[8];
#pragma unroll
        for (int u = 0; u < 8; u++) p[u] = packed[e + 16 * u];
#pragma unroll
        for (int u = 0; u < 8; u++) v[u] = g1[(p[u] & SRC_MASK) * H_DIM + k];
#pragma unroll
        for (int u = 0; u < 8; u++) atomicAdd(&acc[(p[u] >> 17) * H_DIM + k], v[u]);
    }
    for (; e < hi; e += 16) {
        int p0 = packed[e];
        atomicAdd(&acc[(p0 >> 17) * H_DIM + k], g1[(p0 & SRC_MASK) * H_DIM + k]);
    }
    __syncthreads();
    int nbase = b << BUCKET_SHIFT;
    for (int t = threadIdx.x; t < BUCKET_NODES * H_DIM; t += 256) {
        int local = t >> 4, kk = t & 15;
        int n = nbase + local;
        if (n < N) {
            float di = dinv[n];
            float sum = acc[t] + g1[n * H_DIM + kk];  // self-loop
            g2[n * H_DIM + kk] = di * fmaxf(di * sum + b1[kk], 0.0f);
        }
    }
}

// layer 2: s2 = sum + self (dinv, W2, b2 applied in final)
__global__ void __launch_bounds__(256) agg2_kernel(const int* __restrict__ BO,
                                                   const int* __restrict__ packed,
                                                   const float* __restrict__ g2,
                                                   float* __restrict__ s2, int N) {
    __shared__ float acc[BUCKET_NODES * H_DIM];
    int b = blockIdx.x;
    for (int i = threadIdx.x; i < BUCKET_NODES * H_DIM; i += 256) acc[i] = 0.0f;
    __syncthreads();
    int lo = BO[b], hi = BO[b + 1];
    int k = threadIdx.x & 15;
    int eg = threadIdx.x >> 4;
    int e = lo + eg;
    for (; e + 112 < hi; e += 128) {
        int p[8];
        float v[8];
#pragma unroll
        for (int u = 0; u < 8; u++) p[u] = packed[e + 16 * u];
#pragma unroll
        for (int u = 0; u < 8; u++) v[u] = g2[(p[u] & SRC_MASK) * H_DIM + k];
#pragma unroll
        for (int u = 0; u < 8; u++) atomicAdd(&acc[(p[u] >> 17) * H_DIM + k], v[u]);
    }
    for (; e < hi; e += 16) {
        int p0 = packed[e];
        atomicAdd(&acc[(p0 >> 17) * H_DIM + k], g2[(p0 & SRC_MASK) * H_DIM + k]);
    }
    __syncthreads();
    int nbase = b << BUCKET_SHIFT;
    for (int t = threadIdx.x; t < BUCKET_NODES * H_DIM; t += 256) {
        int local = t >> 4, kk = t & 15;
        int n = nbase + local;
        if (n < N) s2[n * H_DIM + kk] = acc[t] + g2[n * H_DIM + kk];
    }
}

// ---------------- final: v = dinv*s2; logits = v@W2 + b2; log_softmax; coalesced writes ----------------

__global__ void __launch_bounds__(256) final_kernel(const float* __restrict__ s2,
                                                    const float* __restrict__ dinv,
                                                    const float* __restrict__ W2,
                                                    const float* __restrict__ b2,
                                                    float* __restrict__ out, int N) {
    __shared__ float w2s[H_DIM * C_DIM];
    __shared__ float b2s[C_DIM];
    __shared__ float stage[256 * 41];
    for (int i = threadIdx.x; i < H_DIM * C_DIM; i += 256) w2s[i] = W2[i];
    if (threadIdx.x < C_DIM) b2s[threadIdx.x] = b2[threadIdx.x];
    __syncthreads();
    int n = blockIdx.x * 256 + threadIdx.x;
    int cn = n < N ? n : 0;
    float di = dinv[cn];
    float v[H_DIM];
    const float4* sv = (const float4*)(s2 + (size_t)cn * H_DIM);
#pragma unroll
    for (int p = 0; p < 4; p++) {
        float4 t = sv[p];
        v[4 * p] = di * t.x; v[4 * p + 1] = di * t.y;
        v[4 * p + 2] = di * t.z; v[4 * p + 3] = di * t.w;
    }
    float lg[C_DIM];
    float m = -1e30f;
    for (int c = 0; c < C_DIM; c++) {
        float a = b2s[c];
#pragma unroll
        for (int k = 0; k < H_DIM; k++) a += v[k] * w2s[k * C_DIM + c];
        lg[c] = a;
        m = fmaxf(m, a);
    }
    float ssum = 0.0f;
    for (int c = 0; c < C_DIM; c++) ssum += __expf(lg[c] - m);
    float lse = m + __logf(ssum);

    size_t base = (size_t)blockIdx.x * 256 * C_DIM;
    size_t lim = (size_t)N * C_DIM;
    for (int c = 0; c < C_DIM; c++) stage[threadIdx.x * 41 + c] = lg[c] - lse;
    __syncthreads();
    for (int i = threadIdx.x; i < 256 * C_DIM; i += 256) {
        int nn = i / C_DIM, c = i - nn * C_DIM;
        size_t g = base + i;
        if (g < lim) out[g] = stage[nn * 41 + c];
    }
    __syncthreads();
    for (int c = 0; c < C_DIM; c++) stage[threadIdx.x * 41 + c] = lg[c];
    __syncthreads();
    for (int i = threadIdx.x; i < 256 * C_DIM; i += 256) {
        int nn = i / C_DIM, c = i - nn * C_DIM;
        size_t g = base + i;
        if (g < lim) out[lim + g] = stage[nn * 41 + c];
    }
}

// ---------------- launch ----------------

extern "C" void kernel_launch(void* const* d_in, const int* in_sizes, int n_in,
                              void* d_out, int out_size, void* d_ws, size_t ws_size,
                              hipStream_t stream) {
    const float* x  = (const float*)d_in[0];
    const int* ei   = (const int*)d_in[1];
    const float* W1 = (const float*)d_in[2];
    const float* b1 = (const float*)d_in[3];
    const float* W2 = (const float*)d_in[4];
    const float* b2 = (const float*)d_in[5];
    float* out = (float*)d_out;

    const int N = N_NODES;
    const int E = in_sizes[1] / 2;
    const int* src = ei;
    const int* dst = ei + E;

    // ws layout: S[N] | BC[1568] | BO[1568] | cursor[1568] | dinv[N] | g1[16N] | g2[16N] | packed[E]  (~26.4 MB)
    int* S      = (int*)d_ws;
    int* BC     = S + N;
    int* BO     = BC + 1568;
    int* cursor = BO + 1568;
    float* dinv = (float*)(cursor + 1568);
    float* g1   = dinv + N;
    float* g2   = g1 + 16 * N;
    int* packed = (int*)(g2 + 16 * N);
    float* s2   = g1;  // g1 dead after agg1

    hipMemsetAsync(S, 0, (size_t)N * sizeof(int), stream);
    hist_kernel<<<(E + 255) / 256, 256, 0, stream>>>(dst, S, E);
    dinv_kernel<<<(N + 255) / 256, 256, 0, stream>>>(S, dinv, N);
    bucket_sum_kernel<<<(NBUCK + 3) / 4, 256, 0, stream>>>(S, BC, N);
    scan_small_kernel<<<1, 1024, 0, stream>>>(BC, BO, cursor);
    partition_kernel<<<(E + CHUNK - 1) / CHUNK, 256, 0, stream>>>(src, dst, cursor, packed, E);

    gemm1_kernel<<<(N + 255) / 256, 256, 0, stream>>>(x, W1, dinv, g1, N);
    agg1_kernel<<<NBUCK, 256, 0, stream>>>(BO, packed, g1, dinv, b1, g2, N);
    agg2_kernel<<<NBUCK, 256, 0, stream>>>(BO, packed, g2, s2, N);
    final_kernel<<<(N + 255) / 256, 256, 0, stream>>>(s2, dinv, W2, b2, out, N);
}

// Round 5
// 655.767 us; speedup vs baseline: 1.8978x; 1.7587x over previous
//
#include <hip/hip_runtime.h>
#include <hip/hip_bf16.h>
#include <math.h>

#define N_NODES 100000
#define F_IN 512
#define H_DIM 16
#define C_DIM 40

#define BSHIFT 9                       // 512 nodes per bucket
#define BNODES 512
#define NBUCK 196                      // ceil(100000 / 512)
#define CHUNK 8192                     // edges per partition block
#define SRC_MASK 0x1FFFF               // 17 bits (N < 131072)

// ---------------- degree histogram / dinv ----------------

__global__ void hist_kernel(const int* __restrict__ dst, int* __restrict__ cnt, int E) {
    int e = blockIdx.x * blockDim.x + threadIdx.x;
    if (e < E) atomicAdd(&cnt[dst[e]], 1);
}

__global__ void dinv_kernel(const int* __restrict__ cnt, float* __restrict__ dinv, int N) {
    int i = blockIdx.x * blockDim.x + threadIdx.x;
    if (i < N) dinv[i] = rsqrtf((float)(cnt[i] + 1));  // +1 = self-loop
}

// ---------------- exclusive scan of S[N] in place (node CSR offsets) ----------------

__global__ void __launch_bounds__(256) scan1_kernel(int* __restrict__ S, int* __restrict__ BS, int N) {
    __shared__ int buf[2][256];
    int tid = threadIdx.x;
    int gi = blockIdx.x * 256 + tid;
    int v = (gi < N) ? S[gi] : 0;
    int cur = 0;
    buf[0][tid] = v;
    __syncthreads();
    for (int off = 1; off < 256; off <<= 1) {
        int t = buf[cur][tid] + ((tid >= off) ? buf[cur][tid - off] : 0);
        cur ^= 1;
        buf[cur][tid] = t;
        __syncthreads();
    }
    int inc = buf[cur][tid];
    if (gi < N) S[gi] = inc - v;               // exclusive
    if (tid == 255) BS[blockIdx.x] = inc;      // block total
}

__global__ void __launch_bounds__(512) scan2_kernel(int* __restrict__ BS, int NB) {
    __shared__ int buf[2][512];
    int tid = threadIdx.x;
    int v = (tid < NB) ? BS[tid] : 0;
    int cur = 0;
    buf[0][tid] = v;
    __syncthreads();
    for (int off = 1; off < 512; off <<= 1) {
        int t = buf[cur][tid] + ((tid >= off) ? buf[cur][tid - off] : 0);
        cur ^= 1;
        buf[cur][tid] = t;
        __syncthreads();
    }
    if (tid < NB) BS[tid] = buf[cur][tid] - v;  // exclusive
}

__global__ void scan3_kernel(int* __restrict__ S, const int* __restrict__ BS, int N) {
    int i = blockIdx.x * blockDim.x + threadIdx.x;
    if (i < N) S[i] += BS[i >> 8];
}

// ---------------- bucket offsets from node offsets; R[N]=E ----------------

__global__ void __launch_bounds__(256) bo_init_kernel(int* __restrict__ R, int* __restrict__ BO,
                                                      int* __restrict__ cursor, int E, int N) {
    int b = threadIdx.x;
    if (b < NBUCK) {
        int v = R[b << BSHIFT];
        BO[b] = v;
        cursor[b] = v;
    }
    if (b == 0) {
        BO[NBUCK] = E;
        R[N] = E;
    }
}

// ---------------- radix partition by dst bucket; packed = (local_dst<<17)|src ----------------

__global__ void __launch_bounds__(256) partition_kernel(const int* __restrict__ src,
                                                        const int* __restrict__ dst,
                                                        int* __restrict__ cursor,
                                                        int* __restrict__ packed, int E) {
    __shared__ int cnt[NBUCK];
    __shared__ int base[NBUCK];
    int start = blockIdx.x * CHUNK;
    int end = start + CHUNK < E ? start + CHUNK : E;
    for (int i = threadIdx.x; i < NBUCK; i += 256) cnt[i] = 0;
    __syncthreads();
    for (int i = start + threadIdx.x; i < end; i += 256)
        atomicAdd(&cnt[dst[i] >> BSHIFT], 1);
    __syncthreads();
    for (int i = threadIdx.x; i < NBUCK; i += 256) {
        int c = cnt[i];
        base[i] = c ? atomicAdd(&cursor[i], c) : 0;
        cnt[i] = 0;  // reuse as local position
    }
    __syncthreads();
    for (int i = start + threadIdx.x; i < end; i += 256) {
        int d = dst[i];
        int b = d >> BSHIFT;
        int p = base[b] + atomicAdd(&cnt[b], 1);
        packed[p] = ((d & (BNODES - 1)) << 17) | src[i];
    }
}

// ---------------- in-bucket counting scatter -> per-node CSR (eidx holds src) ----------------

__global__ void __launch_bounds__(256) sort_kernel(const int* __restrict__ BO,
                                                   const int* __restrict__ packed,
                                                   const int* __restrict__ R,
                                                   int* __restrict__ eidx, int N) {
    __shared__ int cur[BNODES];  // 2 KB: per-node global cursors
    int b = blockIdx.x;
    int nbase = b << BSHIFT;
    for (int j = threadIdx.x; j < BNODES; j += 256) {
        int n = nbase + j;
        cur[j] = (n < N) ? R[n] : 0;
    }
    __syncthreads();
    int lo = BO[b], hi = BO[b + 1];
    for (int e = lo + threadIdx.x; e < hi; e += 256) {
        int p = packed[e];
        int pos = atomicAdd(&cur[p >> 17], 1);
        eidx[pos] = p & SRC_MASK;  // writes stay inside [BO[b], BO[b+1]) — L2-local
    }
}

// ---------------- GEMM1: g1 = (x @ W1) * dinv, 1 row per thread ----------------

__global__ void __launch_bounds__(256) gemm1_kernel(const float* __restrict__ x,
                                                    const float* __restrict__ W1,
                                                    const float* __restrict__ dinv,
                                                    float* __restrict__ g1, int N) {
    __shared__ float w[F_IN * H_DIM];  // 32 KB
    {
        float4* w4s = (float4*)w;
        const float4* W4 = (const float4*)W1;
        for (int i = threadIdx.x; i < F_IN * H_DIM / 4; i += 256) w4s[i] = W4[i];
    }
    __syncthreads();
    int row = blockIdx.x * 256 + threadIdx.x;
    if (row >= N) return;
    const float4* xr = (const float4*)(x + (size_t)row * F_IN);
    float acc[H_DIM];
#pragma unroll
    for (int k = 0; k < H_DIM; k++) acc[k] = 0.0f;
    const float4* w4 = (const float4*)w;
    for (int f4 = 0; f4 < F_IN / 4; ++f4) {
        float4 xv = xr[f4];
        float xs[4] = {xv.x, xv.y, xv.z, xv.w};
#pragma unroll
        for (int q = 0; q < 4; q++) {
            float wq[H_DIM];
#pragma unroll
            for (int p = 0; p < 4; p++) *(float4*)&wq[4 * p] = w4[(f4 * 4 + q) * 4 + p];
            float s = xs[q];
#pragma unroll
            for (int k = 0; k < H_DIM; k++) acc[k] += s * wq[k];
        }
    }
    float di = dinv[row];
    float4* o = (float4*)(g1 + (size_t)row * H_DIM);
#pragma unroll
    for (int p = 0; p < 4; p++)
        o[p] = make_float4(acc[4 * p] * di, acc[4 * p + 1] * di,
                           acc[4 * p + 2] * di, acc[4 * p + 3] * di);
}

// ---------------- node-parallel CSR aggregation, register accumulate, unroll 8 ----------------

// layer 1: g2 = dinv * relu(dinv*(sum + self) + b1)
__global__ void __launch_bounds__(256) agg1_kernel(const int* __restrict__ R,
                                                   const int* __restrict__ eidx,
                                                   const float* __restrict__ g1,
                                                   const float* __restrict__ dinv,
                                                   const float* __restrict__ b1,
                                                   float* __restrict__ g2, int N) {
    int t = blockIdx.x * 256 + threadIdx.x;
    int n = t >> 4;
    if (n >= N) return;
    int k = t & 15;
    int lo = R[n], hi = R[n + 1];
    float sum = g1[t];  // self-loop (g1 = dinv*h1)
    int e = lo;
    for (; e + 8 <= hi; e += 8) {
        int s[8];
        float v[8];
#pragma unroll
        for (int u = 0; u < 8; u++) s[u] = eidx[e + u];
#pragma unroll
        for (int u = 0; u < 8; u++) v[u] = g1[s[u] * H_DIM + k];
#pragma unroll
        for (int u = 0; u < 8; u++) sum += v[u];
    }
    for (; e < hi; ++e) sum += g1[eidx[e] * H_DIM + k];
    float di = dinv[n];
    g2[t] = di * fmaxf(di * sum + b1[k], 0.0f);
}

// layer 2: s2 = sum + self (dinv, W2, b2 applied in final)
__global__ void __launch_bounds__(256) agg2_kernel(const int* __restrict__ R,
                                                   const int* __restrict__ eidx,
                                                   const float* __restrict__ g2,
                                                   float* __restrict__ s2, int N) {
    int t = blockIdx.x * 256 + threadIdx.x;
    int n = t >> 4;
    if (n >= N) return;
    int k = t & 15;
    int lo = R[n], hi = R[n + 1];
    float sum = g2[t];
    int e = lo;
    for (; e + 8 <= hi; e += 8) {
        int s[8];
        float v[8];
#pragma unroll
        for (int u = 0; u < 8; u++) s[u] = eidx[e + u];
#pragma unroll
        for (int u = 0; u < 8; u++) v[u] = g2[s[u] * H_DIM + k];
#pragma unroll
        for (int u = 0; u < 8; u++) sum += v[u];
    }
    for (; e < hi; ++e) sum += g2[eidx[e] * H_DIM + k];
    s2[t] = sum;
}

// ---------------- final: v = dinv*s2; logits = v@W2 + b2; log_softmax; coalesced writes ----------------

__global__ void __launch_bounds__(256) final_kernel(const float* __restrict__ s2,
                                                    const float* __restrict__ dinv,
                                                    const float* __restrict__ W2,
                                                    const float* __restrict__ b2,
                                                    float* __restrict__ out, int N) {
    __shared__ float w2s[H_DIM * C_DIM];
    __shared__ float b2s[C_DIM];
    __shared__ float stage[256 * 41];
    for (int i = threadIdx.x; i < H_DIM * C_DIM; i += 256) w2s[i] = W2[i];
    if (threadIdx.x < C_DIM) b2s[threadIdx.x] = b2[threadIdx.x];
    __syncthreads();
    int n = blockIdx.x * 256 + threadIdx.x;
    int cn = n < N ? n : 0;
    float di = dinv[cn];
    float v[H_DIM];
    const float4* sv = (const float4*)(s2 + (size_t)cn * H_DIM);
#pragma unroll
    for (int p = 0; p < 4; p++) {
        float4 t = sv[p];
        v[4 * p] = di * t.x; v[4 * p + 1] = di * t.y;
        v[4 * p + 2] = di * t.z; v[4 * p + 3] = di * t.w;
    }
    float lg[C_DIM];
    float m = -1e30f;
    for (int c = 0; c < C_DIM; c++) {
        float a = b2s[c];
#pragma unroll
        for (int k = 0; k < H_DIM; k++) a += v[k] * w2s[k * C_DIM + c];
        lg[c] = a;
        m = fmaxf(m, a);
    }
    float ssum = 0.0f;
    for (int c = 0; c < C_DIM; c++) ssum += __expf(lg[c] - m);
    float lse = m + __logf(ssum);

    size_t base = (size_t)blockIdx.x * 256 * C_DIM;
    size_t lim = (size_t)N * C_DIM;
    for (int c = 0; c < C_DIM; c++) stage[threadIdx.x * 41 + c] = lg[c] - lse;
    __syncthreads();
    for (int i = threadIdx.x; i < 256 * C_DIM; i += 256) {
        int nn = i / C_DIM, c = i - nn * C_DIM;
        size_t g = base + i;
        if (g < lim) out[g] = stage[nn * 41 + c];
    }
    __syncthreads();
    for (int c = 0; c < C_DIM; c++) stage[threadIdx.x * 41 + c] = lg[c];
    __syncthreads();
    for (int i = threadIdx.x; i < 256 * C_DIM; i += 256) {
        int nn = i / C_DIM, c = i - nn * C_DIM;
        size_t g = base + i;
        if (g < lim) out[lim + g] = stage[nn * 41 + c];
    }
}

// ---------------- launch ----------------

extern "C" void kernel_launch(void* const* d_in, const int* in_sizes, int n_in,
                              void* d_out, int out_size, void* d_ws, size_t ws_size,
                              hipStream_t stream) {
    const float* x  = (const float*)d_in[0];
    const int* ei   = (const int*)d_in[1];
    const float* W1 = (const float*)d_in[2];
    const float* b1 = (const float*)d_in[3];
    const float* W2 = (const float*)d_in[4];
    const float* b2 = (const float*)d_in[5];
    float* out = (float*)d_out;

    const int N = N_NODES;
    const int E = in_sizes[1] / 2;
    const int* src = ei;
    const int* dst = ei + E;

    // ws layout (ints): R[N+16] | BS[512] | BO[256] | cursor[256] | dinv[N+16] | eidx[E] |
    //                   union{ packed[E]  |  g1[16N] + g2[16N] }     (~26.4 MB total)
    int* R      = (int*)d_ws;                 // degree -> exclusive node offsets (in place)
    int* BS     = R + 100016;
    int* BO     = BS + 512;
    int* cursor = BO + 256;
    float* dinv = (float*)(cursor + 256);
    int* eidx   = (int*)(dinv + 100016);
    int* packed = eidx + E;                   // dead after sort_kernel
    float* g1   = (float*)packed;             // reuses packed region
    float* g2   = g1 + 16 * N;
    float* s2   = g1;                         // g1 dead after agg1

    const int NB = (N + 255) / 256;  // 391

    hipMemsetAsync(R, 0, (size_t)N * sizeof(int), stream);
    hist_kernel<<<(E + 255) / 256, 256, 0, stream>>>(dst, R, E);
    dinv_kernel<<<NB, 256, 0, stream>>>(R, dinv, N);
    scan1_kernel<<<NB, 256, 0, stream>>>(R, BS, N);
    scan2_kernel<<<1, 512, 0, stream>>>(BS, NB);
    scan3_kernel<<<NB, 256, 0, stream>>>(R, BS, N);
    bo_init_kernel<<<1, 256, 0, stream>>>(R, BO, cursor, E, N);
    partition_kernel<<<(E + CHUNK - 1) / CHUNK, 256, 0, stream>>>(src, dst, cursor, packed, E);
    sort_kernel<<<NBUCK, 256, 0, stream>>>(BO, packed, R, eidx, N);

    gemm1_kernel<<<NB, 256, 0, stream>>>(x, W1, dinv, g1, N);
    agg1_kernel<<<(N * 16 + 255) / 256, 256, 0, stream>>>(R, eidx, g1, dinv, b1, g2, N);
    agg2_kernel<<<(N * 16 + 255) / 256, 256, 0, stream>>>(R, eidx, g2, s2, N);
    final_kernel<<<NB, 256, 0, stream>>>(s2, dinv, W2, b2, out, N);
}